// Round 1
// baseline (32859.152 us; speedup 1.0000x reference)
//
#include <hip/hip_runtime.h>

// GRU_781684048417 — fp32 baseline, one persistent kernel.
// Structure: 128 blocks (1 per batch row) x 1024 threads. Each block runs all
// 288 GRU layers x 96 timesteps sequentially; batch rows are fully independent.
// Per step: both matvecs (whh @ h, wih @ x_t) computed with register-stationary
// weights (96 VGPRs/thread worst case), partial sums reduced through LDS,
// 2-wave gate phase. Activations ping through global ws (48KB/block, L2-hot).

#define TPB 1024
#define PARTJ 776      // padded partial-row length (>= 6*128)
#define DACT 128       // activation row stride (max h)

struct GruArgs {
    const float* x;
    const float* g1_wih0; const float* g1_bih0; const float* g1_whh0; const float* g1_bhh0;
    const float* g1_wih;  const float* g1_bih;  const float* g1_whh;  const float* g1_bhh;
    const float* g2_wih0; const float* g2_bih0; const float* g2_whh0; const float* g2_bhh0;
    const float* g2_wih;  const float* g2_bih;  const float* g2_whh;  const float* g2_bhh;
    const float* g3_wih0; const float* g3_bih0; const float* g3_whh0; const float* g3_bhh0;
    const float* g3_wih;  const float* g3_bih;  const float* g3_whh;  const float* g3_bhh;
    const float* d1_w; const float* d1_b;
    const float* d2_w; const float* d2_b;
    const float* d3_w; const float* d3_b;
};

__device__ __forceinline__ float sigmoid_f(float x) {
    return 1.0f / (1.0f + __expf(-x));
}
__device__ __forceinline__ float tanh_f(float x) {
    // overflow-safe: exp(2x)->inf => 1; ->0 => -1
    return 1.0f - 2.0f / (__expf(2.0f * x) + 1.0f);
}

// One GRU layer for this block's batch row.
// H = hidden size, DIN = padded input size (both multiples of 64 here).
// din_true = actual input width (3, 64, or 128); padded region is zero.
// Row order in the combined output vector g[0..6H):
//   [0,H)=hh_r [H,2H)=hh_z [2H,3H)=hh_n [3H,4H)=ih_r [4H,5H)=ih_z [5H,6H)=ih_n
template<int H, int DIN>
__device__ void run_layer(const float* __restrict__ whh, const float* __restrict__ bhh,
                          const float* __restrict__ wih, const float* __restrict__ bih,
                          int din_true,
                          float* __restrict__ actg,
                          float* part, float* gsum, float* hbuf)
{
    const int tid  = threadIdx.x;
    const int lane = tid & 63;
    const int wave = tid >> 6;
    const int m    = wave >> 3;   // 0 = recurrent (whh), 1 = input (wih)
    const int p    = wave & 7;    // k-chunk index (8 chunks)
    constexpr int J    = (3 * H) / 64;          // rows per lane per matrix (3 or 6)
    constexpr int KH   = H / 8;                 // k-chunk size, recurrent
    constexpr int KI   = DIN / 8;               // k-chunk size, input
    constexpr int KMAX = (KI > KH) ? KI : KH;

    // ---- load this thread's weight rows into registers (guarded for padding) ----
    float w[J * KMAX];
    const int jb = J * lane;   // first row within this matrix half
    if (m == 0) {
#pragma unroll
        for (int jj = 0; jj < J; ++jj)
#pragma unroll
            for (int k = 0; k < KH; ++k)
                w[jj * KH + k] = whh[(jb + jj) * H + p * KH + k];
    } else {
#pragma unroll
        for (int jj = 0; jj < J; ++jj)
#pragma unroll
            for (int k = 0; k < KI; ++k) {
                int kg = p * KI + k;
                w[jj * KI + k] = (kg < din_true) ? wih[(jb + jj) * din_true + kg] : 0.0f;
            }
    }

    // bias row of the partial matrix (summed by the sub-reduce every step)
    if (tid < 6 * H)
        part[8 * PARTJ + tid] = (tid < 3 * H) ? bhh[tid] : bih[tid - 3 * H];
    if (tid < H) hbuf[tid] = 0.0f;   // h0 = 0 each layer
    float hprev = 0.0f;
    __syncthreads();

    const int pcol = m * 3 * H + jb;   // first partial column this thread writes

    for (int t = 0; t < 96; ++t) {
        // ---- matvec partials ----
        float acc[J];
#pragma unroll
        for (int jj = 0; jj < J; ++jj) acc[jj] = 0.0f;

        if (m == 0) {
#pragma unroll
            for (int c = 0; c < KH / 4; ++c) {
                float4 v = *(const float4*)&hbuf[p * KH + 4 * c];
#pragma unroll
                for (int jj = 0; jj < J; ++jj) {
                    acc[jj] += w[jj * KH + 4 * c + 0] * v.x;
                    acc[jj] += w[jj * KH + 4 * c + 1] * v.y;
                    acc[jj] += w[jj * KH + 4 * c + 2] * v.z;
                    acc[jj] += w[jj * KH + 4 * c + 3] * v.w;
                }
            }
        } else {
            const float* xrow = actg + t * DACT + p * KI;
#pragma unroll
            for (int c = 0; c < KI / 4; ++c) {
                float4 v = *(const float4*)&xrow[4 * c];
#pragma unroll
                for (int jj = 0; jj < J; ++jj) {
                    acc[jj] += w[jj * KI + 4 * c + 0] * v.x;
                    acc[jj] += w[jj * KI + 4 * c + 1] * v.y;
                    acc[jj] += w[jj * KI + 4 * c + 2] * v.z;
                    acc[jj] += w[jj * KI + 4 * c + 3] * v.w;
                }
            }
        }
#pragma unroll
        for (int jj = 0; jj < J; ++jj)
            part[p * PARTJ + pcol + jj] = acc[jj];
        __syncthreads();

        // ---- sub-reduce across the 8 k-chunks + bias row (float4 quads) ----
        if (tid < (6 * H) / 4) {
            float4 s = *(const float4*)&part[4 * tid];
#pragma unroll
            for (int pp = 1; pp < 9; ++pp) {
                float4 a = *(const float4*)&part[pp * PARTJ + 4 * tid];
                s.x += a.x; s.y += a.y; s.z += a.z; s.w += a.w;
            }
            *(float4*)&gsum[4 * tid] = s;
        }
        __syncthreads();

        // ---- gates + h update ----
        if (tid < H) {
            float hr = gsum[tid];
            float hz = gsum[H + tid];
            float hn = gsum[2 * H + tid];
            float xr = gsum[3 * H + tid];
            float xz = gsum[4 * H + tid];
            float xn = gsum[5 * H + tid];
            float r = sigmoid_f(xr + hr);
            float z = sigmoid_f(xz + hz);
            float n = tanh_f(xn + r * hn);
            float hv = (1.0f - z) * n + z * hprev;
            hprev = hv;
            hbuf[tid] = hv;
            actg[t * DACT + tid] = hv;   // layer output -> next layer's input
        }
        __syncthreads();
    }
}

__global__ __launch_bounds__(TPB) void gru_kernel(GruArgs A, float* __restrict__ ws,
                                                  float* __restrict__ out)
{
    const int b   = blockIdx.x;
    const int tid = threadIdx.x;
    float* actg = ws + (size_t)b * 96 * DACT;

    __shared__ __align__(16) float part[9 * PARTJ];
    __shared__ __align__(16) float gsum[768];
    __shared__ __align__(16) float hbuf[128];

    // init activations: x in cols [0,3), zeros elsewhere (zero-padding makes all
    // layer-0 input widths uniform; h=64 stacks never write cols >= 64)
    for (int i = tid; i < 96 * DACT; i += TPB) {
        int t = i >> 7, c = i & (DACT - 1);
        actg[i] = (c < 3) ? A.x[(b * 96 + t) * 3 + c] : 0.0f;
    }
    __syncthreads();

    // ---- stack 1: h=64 ----
    run_layer<64, 64>(A.g1_whh0, A.g1_bhh0, A.g1_wih0, A.g1_bih0, 3, actg, part, gsum, hbuf);
    for (int l = 0; l < 95; ++l)
        run_layer<64, 64>(A.g1_whh + l * 192 * 64, A.g1_bhh + l * 192,
                          A.g1_wih + l * 192 * 64, A.g1_bih + l * 192, 64,
                          actg, part, gsum, hbuf);

    // ---- stack 2: h=128 ----
    run_layer<128, 128>(A.g2_whh0, A.g2_bhh0, A.g2_wih0, A.g2_bih0, 64, actg, part, gsum, hbuf);
    for (int l = 0; l < 95; ++l)
        run_layer<128, 128>(A.g2_whh + l * 384 * 128, A.g2_bhh + l * 384,
                            A.g2_wih + l * 384 * 128, A.g2_bih + l * 384, 128,
                            actg, part, gsum, hbuf);

    // ---- stack 3: h=64 (layer 0 has din=128) ----
    run_layer<64, 128>(A.g3_whh0, A.g3_bhh0, A.g3_wih0, A.g3_bih0, 128, actg, part, gsum, hbuf);
    for (int l = 0; l < 95; ++l)
        run_layer<64, 64>(A.g3_whh + l * 192 * 64, A.g3_bhh + l * 192,
                          A.g3_wih + l * 192 * 64, A.g3_bih + l * 192, 64,
                          actg, part, gsum, hbuf);

    // ---- dense head on h = y[:, -1, :] (= hbuf[0..64) after the last layer) ----
    if (tid < 64) {
        float s = A.d1_b[tid];
        for (int k = 0; k < 64; ++k) s += A.d1_w[tid * 64 + k] * hbuf[k];
        gsum[tid] = fmaxf(s, 0.0f);
    }
    __syncthreads();
    if (tid < 32) {
        float s = A.d2_b[tid];
        for (int k = 0; k < 64; ++k) s += A.d2_w[tid * 64 + k] * gsum[k];
        gsum[256 + tid] = fmaxf(s, 0.0f);
    }
    __syncthreads();
    if (tid < 250) {
        float s = A.d3_b[tid];
        for (int k = 0; k < 32; ++k) s += A.d3_w[tid * 32 + k] * gsum[256 + k];
        out[b * 250 + tid] = fmaxf(s, 0.0f);
    }
}

extern "C" void kernel_launch(void* const* d_in, const int* in_sizes, int n_in,
                              void* d_out, int out_size, void* d_ws, size_t ws_size,
                              hipStream_t stream)
{
    GruArgs A;
    A.x       = (const float*)d_in[0];
    A.g1_wih0 = (const float*)d_in[1];  A.g1_bih0 = (const float*)d_in[2];
    A.g1_whh0 = (const float*)d_in[3];  A.g1_bhh0 = (const float*)d_in[4];
    A.g1_wih  = (const float*)d_in[5];  A.g1_bih  = (const float*)d_in[6];
    A.g1_whh  = (const float*)d_in[7];  A.g1_bhh  = (const float*)d_in[8];
    A.g2_wih0 = (const float*)d_in[9];  A.g2_bih0 = (const float*)d_in[10];
    A.g2_whh0 = (const float*)d_in[11]; A.g2_bhh0 = (const float*)d_in[12];
    A.g2_wih  = (const float*)d_in[13]; A.g2_bih  = (const float*)d_in[14];
    A.g2_whh  = (const float*)d_in[15]; A.g2_bhh  = (const float*)d_in[16];
    A.g3_wih0 = (const float*)d_in[17]; A.g3_bih0 = (const float*)d_in[18];
    A.g3_whh0 = (const float*)d_in[19]; A.g3_bhh0 = (const float*)d_in[20];
    A.g3_wih  = (const float*)d_in[21]; A.g3_bih  = (const float*)d_in[22];
    A.g3_whh  = (const float*)d_in[23]; A.g3_bhh  = (const float*)d_in[24];
    A.d1_w = (const float*)d_in[25]; A.d1_b = (const float*)d_in[26];
    A.d2_w = (const float*)d_in[27]; A.d2_b = (const float*)d_in[28];
    A.d3_w = (const float*)d_in[29]; A.d3_b = (const float*)d_in[30];

    gru_kernel<<<dim3(128), dim3(TPB), 0, stream>>>(A, (float*)d_ws, (float*)d_out);
}

// Round 2
// 29201.508 us; speedup vs baseline: 1.1253x; 1.1253x over previous
//
#include <hip/hip_runtime.h>

// GRU_781684048417 — fp32, one persistent kernel, round 2.
// 128 blocks (1 per batch row) x 1024 threads; block runs all 288 layers x 96 t.
// Fixes vs round 1 (which spilled weights at VGPR=64 and paid ~3.2GB of scratch
// writes/dispatch):
//  - __launch_bounds__(1024, 4): 4 waves/EU -> 512-VGPR budget, weights stay
//    register-stationary (96 floats worst case).
//  - Transposed partial layout part[p][slot][lane]: lane-stride-1 ds_write_b32
//    (0 bank conflicts), b128 quad tree-reduce; bias folded into p==0 partials.
//  - ih(t+1) software-pipelined against hh(t) (double-buffered part_ih):
//    the input matvec has no h-dependence, so it runs off the critical chain.
//  - Single in-place activation buffer per block (49KB ws): read of act[t+1]
//    (iter t, phase A) always precedes write of act[t+1] (iter t+1, phase C).

#define TPB 1024
#define PIH_STRIDE (8 * 384)   // part_ih buffer stride (max W = 384)

struct GruArgs {
    const float* x;
    const float* g1_wih0; const float* g1_bih0; const float* g1_whh0; const float* g1_bhh0;
    const float* g1_wih;  const float* g1_bih;  const float* g1_whh;  const float* g1_bhh;
    const float* g2_wih0; const float* g2_bih0; const float* g2_whh0; const float* g2_bhh0;
    const float* g2_wih;  const float* g2_bih;  const float* g2_whh;  const float* g2_bhh;
    const float* g3_wih0; const float* g3_bih0; const float* g3_whh0; const float* g3_bhh0;
    const float* g3_wih;  const float* g3_bih;  const float* g3_whh;  const float* g3_bhh;
    const float* d1_w; const float* d1_b;
    const float* d2_w; const float* d2_b;
    const float* d3_w; const float* d3_b;
};

__device__ __forceinline__ float sigmoid_f(float x) {
    return 1.0f / (1.0f + __expf(-x));
}
__device__ __forceinline__ float tanh_f(float x) {
    return 1.0f - 2.0f / (__expf(2.0f * x) + 1.0f);
}

// One GRU layer for this block's batch row.
// H = hidden, DIN = padded input width (64 or 128), din_true = actual (3/64/128).
// Thread roles: wave = tid>>6; m = wave>>3 (0 = whh matvec, 1 = wih matvec);
// p = wave&7 (k-chunk); lane owns J = 3H/64 consecutive rows jb = J*lane.
// Partial layout (LDS): part[p][jj][lane] (lane-stride 1 -> conflict-free).
// Row R of a matvec lives at slot (R%J)*64 + R/J of the reduced gsum half.
template<int H, int DIN>
__device__ void run_layer(const float* __restrict__ whh, const float* __restrict__ bhh,
                          const float* __restrict__ wih, const float* __restrict__ bih,
                          int din_true, float* __restrict__ act,
                          float* part_hh, float* part_ih, float* gsum, float* hbuf)
{
    const int tid  = threadIdx.x;
    const int lane = tid & 63;
    const int wave = tid >> 6;
    const int m    = wave >> 3;
    const int p    = wave & 7;
    constexpr int J  = (3 * H) / 64;        // 3 or 6 rows per lane per matrix
    constexpr int KH = H / 8;               // k-chunk, recurrent
    constexpr int KI = DIN / 8;             // k-chunk, input
    constexpr int KM = (KI > KH) ? KI : KH;
    constexpr int W  = J * 64;              // partial row width (192 or 384)

    const int jb = J * lane;

    // ---- register-stationary weights + bias ----
    float w[J * KM];
    float bias[J];
    if (m == 0) {
#pragma unroll
        for (int jj = 0; jj < J; ++jj) {
#pragma unroll
            for (int c = 0; c < KH / 4; ++c)
                *(float4*)&w[jj * KH + 4 * c] =
                    *(const float4*)&whh[(jb + jj) * H + p * KH + 4 * c];
            bias[jj] = bhh[jb + jj];
        }
    } else {
        if (din_true == DIN) {
#pragma unroll
            for (int jj = 0; jj < J; ++jj)
#pragma unroll
                for (int c = 0; c < KI / 4; ++c)
                    *(float4*)&w[jj * KI + 4 * c] =
                        *(const float4*)&wih[(jb + jj) * DIN + p * KI + 4 * c];
        } else {
#pragma unroll
            for (int jj = 0; jj < J; ++jj)
#pragma unroll
                for (int k = 0; k < KI; ++k) {
                    int kg = p * KI + k;
                    w[jj * KI + k] = (kg < din_true) ? wih[(jb + jj) * din_true + kg] : 0.0f;
                }
        }
#pragma unroll
        for (int jj = 0; jj < J; ++jj) bias[jj] = bih[jb + jj];
    }

    if (tid < H) hbuf[tid] = 0.0f;   // h0 = 0
    float hprev = 0.0f;

    // ---- prologue: ih(0) into part_ih buffer 0 ----
    if (m == 1) {
        float acc[J];
#pragma unroll
        for (int jj = 0; jj < J; ++jj) acc[jj] = (p == 0) ? bias[jj] : 0.0f;
        const float* xr = act + p * KI;   // t = 0
#pragma unroll
        for (int c = 0; c < KI / 4; ++c) {
            float4 v = *(const float4*)&xr[4 * c];
#pragma unroll
            for (int jj = 0; jj < J; ++jj) {
                acc[jj] += w[jj * KI + 4 * c + 0] * v.x;
                acc[jj] += w[jj * KI + 4 * c + 1] * v.y;
                acc[jj] += w[jj * KI + 4 * c + 2] * v.z;
                acc[jj] += w[jj * KI + 4 * c + 3] * v.w;
            }
        }
#pragma unroll
        for (int jj = 0; jj < J; ++jj)
            part_ih[p * W + jj * 64 + lane] = acc[jj];
    }
    __syncthreads();

    for (int t = 0; t < 96; ++t) {
        // ---- phase A: hh(t) [m==0] and pipelined ih(t+1) [m==1] ----
        if (m == 0) {
            float acc[J];
#pragma unroll
            for (int jj = 0; jj < J; ++jj) acc[jj] = (p == 0) ? bias[jj] : 0.0f;
#pragma unroll
            for (int c = 0; c < KH / 4; ++c) {
                float4 v = *(const float4*)&hbuf[p * KH + 4 * c];
#pragma unroll
                for (int jj = 0; jj < J; ++jj) {
                    acc[jj] += w[jj * KH + 4 * c + 0] * v.x;
                    acc[jj] += w[jj * KH + 4 * c + 1] * v.y;
                    acc[jj] += w[jj * KH + 4 * c + 2] * v.z;
                    acc[jj] += w[jj * KH + 4 * c + 3] * v.w;
                }
            }
#pragma unroll
            for (int jj = 0; jj < J; ++jj)
                part_hh[p * W + jj * 64 + lane] = acc[jj];
        } else if (t < 95) {
            float acc[J];
#pragma unroll
            for (int jj = 0; jj < J; ++jj) acc[jj] = (p == 0) ? bias[jj] : 0.0f;
            const float* xr = act + (t + 1) * 128 + p * KI;
#pragma unroll
            for (int c = 0; c < KI / 4; ++c) {
                float4 v = *(const float4*)&xr[4 * c];
#pragma unroll
                for (int jj = 0; jj < J; ++jj) {
                    acc[jj] += w[jj * KI + 4 * c + 0] * v.x;
                    acc[jj] += w[jj * KI + 4 * c + 1] * v.y;
                    acc[jj] += w[jj * KI + 4 * c + 2] * v.z;
                    acc[jj] += w[jj * KI + 4 * c + 3] * v.w;
                }
            }
            float* pi = part_ih + ((t + 1) & 1) * PIH_STRIDE;
#pragma unroll
            for (int jj = 0; jj < J; ++jj)
                pi[p * W + jj * 64 + lane] = acc[jj];
        }
        __syncthreads();

        // ---- phase B: tree-reduce 8 p-rows -> gsum (b128 quads) ----
        constexpr int NR = (2 * W) / 4;
        if (tid < NR) {
            const bool ih = tid >= W / 4;
            const int q = (ih ? tid - W / 4 : tid) * 4;
            const float* src = ih ? (part_ih + (t & 1) * PIH_STRIDE) : part_hh;
            float4 s = *(const float4*)&src[q];
#pragma unroll
            for (int pp = 1; pp < 8; ++pp) {
                float4 a = *(const float4*)&src[pp * W + q];
                s.x += a.x; s.y += a.y; s.z += a.z; s.w += a.w;
            }
            *(float4*)&gsum[(ih ? 384 : 0) + q] = s;
        }
        __syncthreads();

        // ---- phase C: gates + h update ----
        if (tid < H) {
            const int j = tid;
            const int r0 = j,       r1 = H + j,  r2 = 2 * H + j;
            float hr = gsum[(r0 % J) * 64 + r0 / J];
            float hz = gsum[(r1 % J) * 64 + r1 / J];
            float hn = gsum[(r2 % J) * 64 + r2 / J];
            float xr = gsum[384 + (r0 % J) * 64 + r0 / J];
            float xz = gsum[384 + (r1 % J) * 64 + r1 / J];
            float xn = gsum[384 + (r2 % J) * 64 + r2 / J];
            float r = sigmoid_f(xr + hr);
            float z = sigmoid_f(xz + hz);
            float n = tanh_f(xn + r * hn);
            float hv = (1.0f - z) * n + z * hprev;
            hprev = hv;
            hbuf[j] = hv;
            act[t * 128 + j] = hv;   // in-place: act[t] only re-read by NEXT layer
        }
        __syncthreads();
    }
}

__global__ __launch_bounds__(TPB, 4) void gru_kernel(GruArgs A, float* __restrict__ ws,
                                                     float* __restrict__ out)
{
    const int b   = blockIdx.x;
    const int tid = threadIdx.x;
    float* act = ws + (size_t)b * 96 * 128;

    __shared__ __align__(16) float part_hh[8 * 384];
    __shared__ __align__(16) float part_ih[2 * 8 * 384];
    __shared__ __align__(16) float gsum[768];
    __shared__ __align__(16) float hbuf[128];

    // zero activation buffer (cols >= h stay zero => uniform padded reads),
    // then drop x into cols [0,3)
    for (int i = tid; i < 96 * 128; i += TPB) act[i] = 0.0f;
    __syncthreads();
    for (int i = tid; i < 96 * 3; i += TPB) {
        int t = i / 3, c = i - 3 * t;
        act[t * 128 + c] = A.x[(b * 96 + t) * 3 + c];
    }
    __syncthreads();

    // ---- stack 1: h=64 ----
    run_layer<64, 64>(A.g1_whh0, A.g1_bhh0, A.g1_wih0, A.g1_bih0, 3,
                      act, part_hh, part_ih, gsum, hbuf);
    for (int l = 0; l < 95; ++l)
        run_layer<64, 64>(A.g1_whh + l * 192 * 64, A.g1_bhh + l * 192,
                          A.g1_wih + l * 192 * 64, A.g1_bih + l * 192, 64,
                          act, part_hh, part_ih, gsum, hbuf);

    // ---- stack 2: h=128 (layer 0: din_true=64, wih shape (384,64)) ----
    run_layer<128, 128>(A.g2_whh0, A.g2_bhh0, A.g2_wih0, A.g2_bih0, 64,
                        act, part_hh, part_ih, gsum, hbuf);
    for (int l = 0; l < 95; ++l)
        run_layer<128, 128>(A.g2_whh + l * 384 * 128, A.g2_bhh + l * 384,
                            A.g2_wih + l * 384 * 128, A.g2_bih + l * 384, 128,
                            act, part_hh, part_ih, gsum, hbuf);

    // ---- stack 3: h=64 (layer 0: din=128) ----
    run_layer<64, 128>(A.g3_whh0, A.g3_bhh0, A.g3_wih0, A.g3_bih0, 128,
                       act, part_hh, part_ih, gsum, hbuf);
    for (int l = 0; l < 95; ++l)
        run_layer<64, 64>(A.g3_whh + l * 192 * 64, A.g3_bhh + l * 192,
                          A.g3_wih + l * 192 * 64, A.g3_bih + l * 192, 64,
                          act, part_hh, part_ih, gsum, hbuf);

    // ---- dense head on h = hbuf[0..64) ----
    if (tid < 64) {
        float s = A.d1_b[tid];
        for (int k = 0; k < 64; ++k) s += A.d1_w[tid * 64 + k] * hbuf[k];
        gsum[tid] = fmaxf(s, 0.0f);
    }
    __syncthreads();
    if (tid < 32) {
        float s = A.d2_b[tid];
        for (int k = 0; k < 64; ++k) s += A.d2_w[tid * 64 + k] * gsum[k];
        gsum[256 + tid] = fmaxf(s, 0.0f);
    }
    __syncthreads();
    if (tid < 250) {
        float s = A.d3_b[tid];
        for (int k = 0; k < 32; ++k) s += A.d3_w[tid * 32 + k] * gsum[256 + k];
        out[b * 250 + tid] = fmaxf(s, 0.0f);
    }
}

extern "C" void kernel_launch(void* const* d_in, const int* in_sizes, int n_in,
                              void* d_out, int out_size, void* d_ws, size_t ws_size,
                              hipStream_t stream)
{
    GruArgs A;
    A.x       = (const float*)d_in[0];
    A.g1_wih0 = (const float*)d_in[1];  A.g1_bih0 = (const float*)d_in[2];
    A.g1_whh0 = (const float*)d_in[3];  A.g1_bhh0 = (const float*)d_in[4];
    A.g1_wih  = (const float*)d_in[5];  A.g1_bih  = (const float*)d_in[6];
    A.g1_whh  = (const float*)d_in[7];  A.g1_bhh  = (const float*)d_in[8];
    A.g2_wih0 = (const float*)d_in[9];  A.g2_bih0 = (const float*)d_in[10];
    A.g2_whh0 = (const float*)d_in[11]; A.g2_bhh0 = (const float*)d_in[12];
    A.g2_wih  = (const float*)d_in[13]; A.g2_bih  = (const float*)d_in[14];
    A.g2_whh  = (const float*)d_in[15]; A.g2_bhh  = (const float*)d_in[16];
    A.g3_wih0 = (const float*)d_in[17]; A.g3_bih0 = (const float*)d_in[18];
    A.g3_whh0 = (const float*)d_in[19]; A.g3_bhh0 = (const float*)d_in[20];
    A.g3_wih  = (const float*)d_in[21]; A.g3_bih  = (const float*)d_in[22];
    A.g3_whh  = (const float*)d_in[23]; A.g3_bhh  = (const float*)d_in[24];
    A.d1_w = (const float*)d_in[25]; A.d1_b = (const float*)d_in[26];
    A.d2_w = (const float*)d_in[27]; A.d2_b = (const float*)d_in[28];
    A.d3_w = (const float*)d_in[29]; A.d3_b = (const float*)d_in[30];

    gru_kernel<<<dim3(128), dim3(TPB), 0, stream>>>(A, (float*)d_ws, (float*)d_out);
}

// Round 3
// 18463.298 us; speedup vs baseline: 1.7797x; 1.5816x over previous
//
#include <hip/hip_runtime.h>

// GRU_781684048417 — round 3: layer-pipelined wavefront, fp32 VALU cells.
//
// Structure: the (layer, t) dependency graph is a wavefront — layer l at time t
// needs layer l-1 at time t and itself at t-1. One block per (layer, slice);
// weights staged ONCE into LDS (no VGPR spill gamble), reused for all 96 steps.
// Cross-block producer/consumer via agent-scope acquire/release flags + depth-4
// rings in ws. Every pass: 192 blocks, 1 block/CU (LDS 131-147KB) -> all
// co-resident -> spin-waits are deadlock-free.
// Passes: s1 (96 layers x 2 batch-halves), s2a/s2b (48 layers x 4 row-slices),
// s3 (96 x 2), head. Cells are register-tiled GEMMs (6 gate-rows x 4 batch per
// thread) reading weights from LDS with broadcast b64/b128 -> VALU-bound.

#define TPB 512
#define DRING 4

__device__ __forceinline__ float sigmoid_f(float x) { return 1.0f / (1.0f + __expf(-x)); }
__device__ __forceinline__ float tanh_f(float x)    { return 1.0f - 2.0f / (__expf(2.0f * x) + 1.0f); }

__device__ __forceinline__ int ld_flag(int* p) {
    return __hip_atomic_load(p, __ATOMIC_ACQUIRE, __HIP_MEMORY_SCOPE_AGENT);
}
__device__ __forceinline__ void st_flag(int* p, int v) {
    __hip_atomic_store(p, v, __ATOMIC_RELEASE, __HIP_MEMORY_SCOPE_AGENT);
}

struct PassArgs {
    const float* wih0; const float* bih0; const float* whh0; const float* bhh0;
    const float* wihA; const float* bihA; const float* whhA; const float* bhhA;
    int firstLayer;          // global layer index of this pass's layer 0
    int NL;                  // layers in this pass
    const float* seqIn;      // input sequence buffer [96][seqK][128]
    long seqTs;              // t-stride of seqIn (seqK*128)
    float* seqOut;           // output seq buffer [96][128][128] or null
    float* hFinal;           // stack3 only
    float* rings;            // [192][DRING][4096]
    int* done;               // [192][16] this pass's flags
};

// STACK: 1, 2, 3
template<int STACK>
__global__ __launch_bounds__(TPB, 2) void pass_kernel(PassArgs A)
{
    constexpr int NG    = (STACK == 2) ? 96 : 192;   // gate rows per block
    constexpr int NB    = (STACK == 2) ? 128 : 64;   // batch rows per block
    constexpr int KH    = (STACK == 2) ? 128 : 64;   // recurrent K
    constexpr int PARTS = (STACK == 2) ? 4 : 2;
    constexpr int JS    = NG / 3;                    // gate-group stride (r|z|n)
    constexpr int NGG   = NG / 6;                    // 6 rows per thread

    __shared__ float wt_hh[KH * NG];                 // 12288 floats (49KB)
    __shared__ float wt_ih[((STACK == 2) ? 128 : 64) * NG]; // 12288 floats
    __shared__ float atile[64 * NB];                 // act k-tile
    __shared__ float hbuf[64 * 64];                  // stacks 1/3: own h

    const int tid  = threadIdx.x;
    const int rb   = blockIdx.x;
    const int l    = rb / PARTS;
    const int part = rb % PARTS;
    const int gl   = A.firstLayer + l;

    const int gg = tid & (NGG - 1);
    const int bg = tid / NGG;
    const int jl0 = 2 * gg, jl1 = 2 * gg + 1;
    const int b0 = 4 * bg;

    // ---- layer weight pointers ----
    const float *wih, *bih, *whh, *bhh;
    int din;   // true input width of this layer
    if (gl == 0) { wih = A.wih0; bih = A.bih0; whh = A.whh0; bhh = A.bhh0;
                   din = (STACK == 1) ? 3 : ((STACK == 2) ? 64 : 128); }
    else {
        const int ws_ih = (STACK == 2) ? 384 * 128 : 192 * 64;
        const int ws_hh = ws_ih;
        const int bs    = (STACK == 2) ? 384 : 192;
        wih = A.wihA + (size_t)(gl - 1) * ws_ih; bih = A.bihA + (size_t)(gl - 1) * bs;
        whh = A.whhA + (size_t)(gl - 1) * ws_hh; bhh = A.bhhA + (size_t)(gl - 1) * bs;
        din = (STACK == 2) ? 128 : 64;
    }
    const bool wideIH = (STACK == 3) && (gl == 0);   // din=128 > LDS ih cap: restage per k-tile

    // local gate row -> global weight row
    auto grow = [&](int r) -> int {
        if (STACK == 2) return (r >> 5) * 128 + 32 * part + (r & 31);
        return r;
    };

    // ---- stage weights into LDS (transposed [k][row]); once per pass ----
    for (int i = tid; i < NG * KH; i += TPB) {
        int r = i / KH, k = i - r * KH;
        wt_hh[k * NG + r] = whh[(size_t)grow(r) * KH + k];
    }
    if (!wideIH) {
        constexpr int KI = (STACK == 2) ? 128 : 64;
        for (int i = tid; i < NG * KI; i += TPB) {
            int r = i / KI, k = i - r * KI;
            wt_ih[k * NG + r] = (k < din) ? wih[(size_t)grow(r) * din + k] : 0.0f;
        }
    }

    // ---- biases (thread-local rows) ----
    float bR[2], bZ[2], bNH[2], bNI[2];
#pragma unroll
    for (int jj = 0; jj < 2; ++jj) {
        int jl = jl0 + jj;
        bR[jj]  = bhh[grow(jl)]          + bih[grow(jl)];
        bZ[jj]  = bhh[grow(JS + jl)]     + bih[grow(JS + jl)];
        bNH[jj] = bhh[grow(2 * JS + jl)];
        bNI[jj] = bih[grow(2 * JS + jl)];
    }

    float hprev[2][4];
#pragma unroll
    for (int jj = 0; jj < 2; ++jj)
#pragma unroll
        for (int bb = 0; bb < 4; ++bb) hprev[jj][bb] = 0.0f;

    __syncthreads();

    // ---- GEMM over one 64-k tile ----
    auto gemm64 = [&](const float* wt, const float* at, int astride,
                      float (&accR)[2][4], float (&accZ)[2][4], float (&accN)[2][4]) {
#pragma unroll 4
        for (int k = 0; k < 64; ++k) {
            const float* wr = wt + k * NG;
            float2 wR = *(const float2*)&wr[jl0];
            float2 wZ = *(const float2*)&wr[JS + jl0];
            float2 wN = *(const float2*)&wr[2 * JS + jl0];
            float4 av = *(const float4*)(at + k * astride + b0);
            float a[4] = {av.x, av.y, av.z, av.w};
#pragma unroll
            for (int bb = 0; bb < 4; ++bb) {
                accR[0][bb] += wR.x * a[bb];  accR[1][bb] += wR.y * a[bb];
                accZ[0][bb] += wZ.x * a[bb];  accZ[1][bb] += wZ.y * a[bb];
                accN[0][bb] += wN.x * a[bb];  accN[1][bb] += wN.y * a[bb];
            }
        }
    };

    const int nih = (STACK == 2 || wideIH) ? 2 : 1;

    for (int t = 0; t < 96; ++t) {
        // ---- waits: parents(t+1), sibs(t), children(t-DRING+1) ----
        if (tid < 12) {
            int grp = tid >> 2, idx = tid & 3;
            int* fp = nullptr; int tgt = 0;
            bool rel = (STACK == 2) ? (idx < PARTS) : (idx == part);
            if (grp == 0) { if (l > 0 && rel) { fp = &A.done[((l - 1) * PARTS + idx) * 16]; tgt = t + 1; } }
            else if (grp == 1) { if (STACK == 2 && t >= 1 && idx < PARTS && idx != part)
                                 { fp = &A.done[(l * PARTS + idx) * 16]; tgt = t; } }
            else { if (t >= DRING && l < A.NL - 1 && rel)
                   { fp = &A.done[((l + 1) * PARTS + idx) * 16]; tgt = t - DRING + 1; } }
            if (fp) while (ld_flag(fp) < tgt) __builtin_amdgcn_s_sleep(8);
        }
        __syncthreads();

        float accR[2][4] = {}, accZ[2][4] = {}, accNH[2][4] = {}, accNI[2][4] = {};

        // ---- hh phase (skip t=0: h_prev = 0) ----
        if (t > 0) {
            if (STACK == 2) {
                for (int kt = 0; kt < 2; ++kt) {
                    // own-layer slices, step t-1, from rings
                    for (int i = tid; i < 2048; i += TPB) {
                        int r = i >> 5, seg = i & 31;
                        int kk = kt * 64 + r;
                        const float* src = A.rings
                            + ((size_t)(l * 4 + (kk >> 5)) * DRING + ((t - 1) & 3)) * 4096
                            + (kk & 31) * 128 + seg * 4;
                        *(float4*)&atile[r * 128 + seg * 4] = *(const float4*)src;
                    }
                    __syncthreads();
                    gemm64(wt_hh + kt * 64 * NG, atile, 128, accR, accZ, accNH);
                    __syncthreads();
                }
            } else {
                gemm64(wt_hh, hbuf, 64, accR, accZ, accNH);
            }
        }

        // ---- ih phase ----
        for (int kt = 0; kt < nih; ++kt) {
            if (STACK == 2 && l == 0 && A.firstLayer == 0 && kt == 1) break; // zero pad region
            __syncthreads();
            if (wideIH) {   // stack3 l0: restage ih weights for this k-tile
                for (int i = tid; i < 192 * 64; i += TPB) {
                    int r = i >> 6, k = i & 63;
                    wt_ih[k * NG + r] = wih[(size_t)r * 128 + kt * 64 + k];
                }
            }
            if (l == 0) {   // from sequence buffer
                const float* src = A.seqIn + (size_t)t * A.seqTs + (size_t)kt * 64 * 128
                                 + ((STACK == 2) ? 0 : 64 * part);
                if (STACK == 2) {
                    for (int i = tid; i < 2048; i += TPB) {
                        int r = i >> 5, seg = i & 31;
                        *(float4*)&atile[r * 128 + seg * 4] = *(const float4*)(src + r * 128 + seg * 4);
                    }
                } else {
                    for (int i = tid; i < 1024; i += TPB) {
                        int r = i >> 4, seg = i & 15;
                        *(float4*)&atile[r * 64 + seg * 4] = *(const float4*)(src + r * 128 + seg * 4);
                    }
                }
            } else {        // from parent ring, step t
                if (STACK == 2) {
                    for (int i = tid; i < 2048; i += TPB) {
                        int r = i >> 5, seg = i & 31;
                        int kk = kt * 64 + r;
                        const float* src = A.rings
                            + ((size_t)((l - 1) * 4 + (kk >> 5)) * DRING + (t & 3)) * 4096
                            + (kk & 31) * 128 + seg * 4;
                        *(float4*)&atile[r * 128 + seg * 4] = *(const float4*)src;
                    }
                } else {
                    const float* src = A.rings + ((size_t)((l - 1) * 2 + part) * DRING + (t & 3)) * 4096;
                    for (int i = tid; i < 1024; i += TPB)
                        *(float4*)&atile[i * 4] = *(const float4*)(src + i * 4);
                }
            }
            __syncthreads();
            gemm64(wt_ih + (wideIH ? 0 : kt * 64 * NG), atile, NB, accR, accZ, accNI);
        }

        // ---- gates + h update + publish ----
        float4 hv[2];
#pragma unroll
        for (int jj = 0; jj < 2; ++jj) {
            float* hp = (float*)&hv[jj];
#pragma unroll
            for (int bb = 0; bb < 4; ++bb) {
                float r = sigmoid_f(accR[jj][bb] + bR[jj]);
                float z = sigmoid_f(accZ[jj][bb] + bZ[jj]);
                float n = tanh_f(accNI[jj][bb] + bNI[jj] + r * (accNH[jj][bb] + bNH[jj]));
                float h = (1.0f - z) * n + z * hprev[jj][bb];
                hprev[jj][bb] = h;
                hp[bb] = h;
            }
        }
        float* slot = A.rings + ((size_t)rb * DRING + (t & 3)) * 4096;
        if (STACK == 2) {
            *(float4*)&slot[jl0 * 128 + b0] = hv[0];
            *(float4*)&slot[jl1 * 128 + b0] = hv[1];
            if (A.seqOut && l == A.NL - 1) {
                *(float4*)&A.seqOut[(size_t)t * 16384 + (32 * part + jl0) * 128 + b0] = hv[0];
                *(float4*)&A.seqOut[(size_t)t * 16384 + (32 * part + jl1) * 128 + b0] = hv[1];
            }
        } else {
            *(float4*)&slot[jl0 * 64 + b0] = hv[0];
            *(float4*)&slot[jl1 * 64 + b0] = hv[1];
            *(float4*)&hbuf[jl0 * 64 + b0] = hv[0];
            *(float4*)&hbuf[jl1 * 64 + b0] = hv[1];
            if (A.seqOut && l == A.NL - 1) {
                *(float4*)&A.seqOut[(size_t)t * 16384 + jl0 * 128 + 64 * part + b0] = hv[0];
                *(float4*)&A.seqOut[(size_t)t * 16384 + jl1 * 128 + 64 * part + b0] = hv[1];
            }
            if (STACK == 3 && l == A.NL - 1 && t == 95 && A.hFinal) {
                *(float4*)&A.hFinal[jl0 * 128 + 64 * part + b0] = hv[0];
                *(float4*)&A.hFinal[jl1 * 128 + 64 * part + b0] = hv[1];
            }
        }
        __syncthreads();
        if (tid == 0) st_flag(&A.done[rb * 16], t + 1);
    }
}

// x (128,96,3) -> seqA[t][k][b], k<3 (rest is memset-zero)
__global__ void xprep_kernel(const float* __restrict__ x, float* __restrict__ seqA)
{
    int i = blockIdx.x * 256 + threadIdx.x;
    if (i < 128 * 96 * 3) {
        int b = i / 288, r = i - b * 288;
        int t = r / 3, k = r - 3 * t;
        seqA[(size_t)t * 8192 + k * 128 + b] = x[i];
    }
}

__global__ __launch_bounds__(256) void head_kernel(
    const float* __restrict__ hF,
    const float* __restrict__ d1w, const float* __restrict__ d1b,
    const float* __restrict__ d2w, const float* __restrict__ d2b,
    const float* __restrict__ d3w, const float* __restrict__ d3b,
    float* __restrict__ out)
{
    const int b = blockIdx.x, tid = threadIdx.x;
    __shared__ float h1[64], h2[32];
    if (tid < 64) {
        float s = d1b[tid];
        for (int k = 0; k < 64; ++k) s += d1w[tid * 64 + k] * hF[k * 128 + b];
        h1[tid] = fmaxf(s, 0.0f);
    }
    __syncthreads();
    if (tid < 32) {
        float s = d2b[tid];
        for (int k = 0; k < 64; ++k) s += d2w[tid * 64 + k] * h1[k];
        h2[tid] = fmaxf(s, 0.0f);
    }
    __syncthreads();
    if (tid < 250) {
        float s = d3b[tid];
        for (int k = 0; k < 32; ++k) s += d3w[tid * 32 + k] * h2[k];
        out[b * 250 + tid] = fmaxf(s, 0.0f);
    }
}

extern "C" void kernel_launch(void* const* d_in, const int* in_sizes, int n_in,
                              void* d_out, int out_size, void* d_ws, size_t ws_size,
                              hipStream_t stream)
{
    const float* x       = (const float*)d_in[0];
    const float* g1_wih0 = (const float*)d_in[1];  const float* g1_bih0 = (const float*)d_in[2];
    const float* g1_whh0 = (const float*)d_in[3];  const float* g1_bhh0 = (const float*)d_in[4];
    const float* g1_wih  = (const float*)d_in[5];  const float* g1_bih  = (const float*)d_in[6];
    const float* g1_whh  = (const float*)d_in[7];  const float* g1_bhh  = (const float*)d_in[8];
    const float* g2_wih0 = (const float*)d_in[9];  const float* g2_bih0 = (const float*)d_in[10];
    const float* g2_whh0 = (const float*)d_in[11]; const float* g2_bhh0 = (const float*)d_in[12];
    const float* g2_wih  = (const float*)d_in[13]; const float* g2_bih  = (const float*)d_in[14];
    const float* g2_whh  = (const float*)d_in[15]; const float* g2_bhh  = (const float*)d_in[16];
    const float* g3_wih0 = (const float*)d_in[17]; const float* g3_bih0 = (const float*)d_in[18];
    const float* g3_whh0 = (const float*)d_in[19]; const float* g3_bhh0 = (const float*)d_in[20];
    const float* g3_wih  = (const float*)d_in[21]; const float* g3_bih  = (const float*)d_in[22];
    const float* g3_whh  = (const float*)d_in[23]; const float* g3_bhh  = (const float*)d_in[24];
    const float* d1w = (const float*)d_in[25]; const float* d1b = (const float*)d_in[26];
    const float* d2w = (const float*)d_in[27]; const float* d2b = (const float*)d_in[28];
    const float* d3w = (const float*)d_in[29]; const float* d3b = (const float*)d_in[30];

    float* wsf = (float*)d_ws;
    const size_t RINGS = (size_t)192 * DRING * 4096;   // 3,145,728 fl
    const size_t B1SZ  = (size_t)96 * 128 * 128;       // 1,572,864 fl
    const size_t SEQA  = (size_t)96 * 64 * 128;        //   786,432 fl
    float* rings  = wsf;
    float* B1     = rings + RINGS;
    float* B2     = B1 + B1SZ;
    float* seqA   = B2 + B1SZ;
    float* hFinal = seqA + SEQA;
    int*   flags  = (int*)(hFinal + 8192);             // 4 passes x 192 x 16 ints

    // zero B1 (incl. k>=64 pad rows), B2, seqA (pad), hFinal, flags — one range
    size_t zero_bytes = (B1SZ * 2 + SEQA + 8192) * sizeof(float) + 4 * 192 * 16 * sizeof(int);
    hipMemsetAsync(B1, 0, zero_bytes, stream);

    xprep_kernel<<<dim3(144), dim3(256), 0, stream>>>(x, seqA);

    PassArgs P;
    // ---- pass 1: stack1, 96 layers x 2 batch-halves ----
    P = {g1_wih0, g1_bih0, g1_whh0, g1_bhh0, g1_wih, g1_bih, g1_whh, g1_bhh,
         0, 96, seqA, 8192, B1, nullptr, rings, flags + 0 * 192 * 16};
    pass_kernel<1><<<dim3(192), dim3(TPB), 0, stream>>>(P);

    // ---- pass 2a: stack2 layers 0..47, 4 row-slices ----
    P = {g2_wih0, g2_bih0, g2_whh0, g2_bhh0, g2_wih, g2_bih, g2_whh, g2_bhh,
         0, 48, B1, 16384, B2, nullptr, rings, flags + 1 * 192 * 16};
    pass_kernel<2><<<dim3(192), dim3(TPB), 0, stream>>>(P);

    // ---- pass 2b: stack2 layers 48..95 ----
    P = {g2_wih0, g2_bih0, g2_whh0, g2_bhh0, g2_wih, g2_bih, g2_whh, g2_bhh,
         48, 48, B2, 16384, B1, nullptr, rings, flags + 2 * 192 * 16};
    pass_kernel<2><<<dim3(192), dim3(TPB), 0, stream>>>(P);

    // ---- pass 3: stack3, 96 layers x 2 batch-halves ----
    P = {g3_wih0, g3_bih0, g3_whh0, g3_bhh0, g3_wih, g3_bih, g3_whh, g3_bhh,
         0, 96, B1, 16384, nullptr, hFinal, rings, flags + 3 * 192 * 16};
    pass_kernel<3><<<dim3(192), dim3(TPB), 0, stream>>>(P);

    head_kernel<<<dim3(128), dim3(256), 0, stream>>>(hFinal, d1w, d1b, d2w, d2b, d3w, d3b,
                                                     (float*)d_out);
}

// Round 4
// 13984.331 us; speedup vs baseline: 2.3497x; 1.3203x over previous
//
#include <hip/hip_runtime.h>

// GRU_781684048417 — round 4: layer-pipelined wavefront, cheap sync protocol.
//
// Topology identical to round 3 (one block per (layer, slice); LDS-stationary
// weights; depth-4 rings; 4 passes of 192 co-resident blocks). Round 3 measured
// VALUBusy=9.8% with per-FMA time matching the model => ~80% of wall time was
// the handshake: acquire-polls (buffer_inv per poll!) + release stores
// (buffer_wbl2) + parent-flag RTT sitting on every critical-path link.
// Fixes:
//  - Polls are RELAXED agent-scope atomic loads (coherent, no cache inv),
//    one ACQUIRE load on success.
//  - Ring reads are RELAXED agent-scope 8B atomic loads (always fetch the
//    coherence point -> no stale L2, no invalidates). Ring writes stay plain;
//    the one RELEASE flag store per step (wbl2) publishes them.
//  - hh-gemm (no cross-block dep) runs BEFORE the parent wait each step, so
//    the flag RTT hides under compute.

#define TPB 512
#define DRING 4

__device__ __forceinline__ float sigmoid_f(float x) { return 1.0f / (1.0f + __expf(-x)); }
__device__ __forceinline__ float tanh_f(float x)    { return 1.0f - 2.0f / (__expf(2.0f * x) + 1.0f); }

__device__ __forceinline__ void wait_flag(int* fp, int tgt) {
    while (__hip_atomic_load(fp, __ATOMIC_RELAXED, __HIP_MEMORY_SCOPE_AGENT) < tgt)
        __builtin_amdgcn_s_sleep(2);
    (void)__hip_atomic_load(fp, __ATOMIC_ACQUIRE, __HIP_MEMORY_SCOPE_AGENT);
}
__device__ __forceinline__ float2 ld_remote2(const float* p) {
    unsigned long long u = __hip_atomic_load((const unsigned long long*)p,
                                             __ATOMIC_RELAXED, __HIP_MEMORY_SCOPE_AGENT);
    union { unsigned long long u; float2 f; } c; c.u = u;
    return c.f;
}

struct PassArgs {
    const float* wih0; const float* bih0; const float* whh0; const float* bhh0;
    const float* wihA; const float* bihA; const float* whhA; const float* bhhA;
    int firstLayer;
    int NL;
    const float* seqIn;
    long seqTs;
    float* seqOut;
    float* hFinal;
    float* rings;            // [192][DRING][4096]
    int* done;               // [192][16]
};

template<int STACK>
__global__ __launch_bounds__(TPB, 2) void pass_kernel(PassArgs A)
{
    constexpr int NG    = (STACK == 2) ? 96 : 192;   // gate rows per block
    constexpr int NB    = (STACK == 2) ? 128 : 64;   // batch rows per block
    constexpr int KH    = (STACK == 2) ? 128 : 64;   // recurrent K
    constexpr int PARTS = (STACK == 2) ? 4 : 2;
    constexpr int JS    = NG / 3;
    constexpr int NGG   = NG / 6;

    __shared__ float wt_hh[KH * NG];
    __shared__ float wt_ih[((STACK == 2) ? 128 : 64) * NG];
    __shared__ float atile[64 * NB];
    __shared__ float hbuf[64 * 64];

    const int tid  = threadIdx.x;
    const int rb   = blockIdx.x;
    const int l    = rb / PARTS;
    const int part = rb % PARTS;
    const int gl   = A.firstLayer + l;

    const int gg = tid & (NGG - 1);
    const int bg = tid / NGG;
    const int jl0 = 2 * gg, jl1 = 2 * gg + 1;
    const int b0 = 4 * bg;

    const float *wih, *bih, *whh, *bhh;
    int din;
    if (gl == 0) { wih = A.wih0; bih = A.bih0; whh = A.whh0; bhh = A.bhh0;
                   din = (STACK == 1) ? 3 : ((STACK == 2) ? 64 : 128); }
    else {
        const int wsz = (STACK == 2) ? 384 * 128 : 192 * 64;
        const int bs  = (STACK == 2) ? 384 : 192;
        wih = A.wihA + (size_t)(gl - 1) * wsz; bih = A.bihA + (size_t)(gl - 1) * bs;
        whh = A.whhA + (size_t)(gl - 1) * wsz; bhh = A.bhhA + (size_t)(gl - 1) * bs;
        din = (STACK == 2) ? 128 : 64;
    }
    const bool wideIH = (STACK == 3) && (gl == 0);

    auto grow = [&](int r) -> int {
        if (STACK == 2) return (r >> 5) * 128 + 32 * part + (r & 31);
        return r;
    };

    for (int i = tid; i < NG * KH; i += TPB) {
        int r = i / KH, k = i - r * KH;
        wt_hh[k * NG + r] = whh[(size_t)grow(r) * KH + k];
    }
    if (!wideIH) {
        constexpr int KI = (STACK == 2) ? 128 : 64;
        for (int i = tid; i < NG * KI; i += TPB) {
            int r = i / KI, k = i - r * KI;
            wt_ih[k * NG + r] = (k < din) ? wih[(size_t)grow(r) * din + k] : 0.0f;
        }
    }

    float bR[2], bZ[2], bNH[2], bNI[2];
#pragma unroll
    for (int jj = 0; jj < 2; ++jj) {
        int jl = jl0 + jj;
        bR[jj]  = bhh[grow(jl)]          + bih[grow(jl)];
        bZ[jj]  = bhh[grow(JS + jl)]     + bih[grow(JS + jl)];
        bNH[jj] = bhh[grow(2 * JS + jl)];
        bNI[jj] = bih[grow(2 * JS + jl)];
    }

    float hprev[2][4];
#pragma unroll
    for (int jj = 0; jj < 2; ++jj)
#pragma unroll
        for (int bb = 0; bb < 4; ++bb) hprev[jj][bb] = 0.0f;

    __syncthreads();

    auto gemm64 = [&](const float* wt, const float* at, int astride,
                      float (&accR)[2][4], float (&accZ)[2][4], float (&accN)[2][4]) {
#pragma unroll 4
        for (int k = 0; k < 64; ++k) {
            const float* wr = wt + k * NG;
            float2 wR = *(const float2*)&wr[jl0];
            float2 wZ = *(const float2*)&wr[JS + jl0];
            float2 wN = *(const float2*)&wr[2 * JS + jl0];
            float4 av = *(const float4*)(at + k * astride + b0);
            float a[4] = {av.x, av.y, av.z, av.w};
#pragma unroll
            for (int bb = 0; bb < 4; ++bb) {
                accR[0][bb] += wR.x * a[bb];  accR[1][bb] += wR.y * a[bb];
                accZ[0][bb] += wZ.x * a[bb];  accZ[1][bb] += wZ.y * a[bb];
                accN[0][bb] += wN.x * a[bb];  accN[1][bb] += wN.y * a[bb];
            }
        }
    };

    for (int t = 0; t < 96; ++t) {
        float accR[2][4] = {}, accZ[2][4] = {}, accNH[2][4] = {}, accNI[2][4] = {};

        if (STACK != 2) {
            // ---- hh first (own LDS state; hides parent flag RTT) ----
            if (t > 0) gemm64(wt_hh, hbuf, 64, accR, accZ, accNH);

            // ---- parent(t) + child-antidep waits ----
            if (tid < 8) {
                int grp = tid >> 2, idx = tid & 3;
                int* fp = nullptr; int tgt = 0;
                if (grp == 0) { if (l > 0 && idx == part)
                                { fp = &A.done[((l - 1) * PARTS + idx) * 16]; tgt = t + 1; } }
                else          { if (t >= DRING && l < A.NL - 1 && idx == part)
                                { fp = &A.done[((l + 1) * PARTS + idx) * 16]; tgt = t - DRING + 1; } }
                if (fp) wait_flag(fp, tgt);
            }
            __syncthreads();

            // ---- ih: stage + gemm ----
            const int nkt = wideIH ? 2 : 1;
            for (int kt = 0; kt < nkt; ++kt) {
                if (kt) __syncthreads();
                if (wideIH) {
                    for (int i = tid; i < 192 * 64; i += TPB) {
                        int r = i >> 6, k = i & 63;
                        wt_ih[k * NG + r] = wih[(size_t)r * 128 + kt * 64 + k];
                    }
                }
                if (l == 0) {
                    const float* src = A.seqIn + (size_t)t * A.seqTs + (size_t)kt * 64 * 128 + 64 * part;
                    for (int i = tid; i < 1024; i += TPB) {
                        int r = i >> 4, seg = i & 15;
                        *(float4*)&atile[r * 64 + seg * 4] = *(const float4*)(src + r * 128 + seg * 4);
                    }
                } else {
                    const float* slot = A.rings + ((size_t)((l - 1) * PARTS + part) * DRING + (t & 3)) * 4096;
                    for (int u = tid; u < 2048; u += TPB)
                        *(float2*)&atile[2 * u] = ld_remote2(slot + 2 * u);
                }
                __syncthreads();
                gemm64(wt_ih, atile, 64, accR, accZ, accNI);
            }
        } else {
            // ---- STACK 2: sibling wait + hh from rings ----
            if (t > 0) {
                if (tid < 4 && tid != part)
                    wait_flag(&A.done[(l * 4 + tid) * 16], t);
                __syncthreads();
                for (int kt = 0; kt < 2; ++kt) {
                    if (kt) __syncthreads();
                    for (int u = tid; u < 4096; u += TPB) {
                        int r = u >> 6, c2 = u & 63;
                        int kk = kt * 64 + r;
                        const float* src = A.rings
                            + ((size_t)(l * 4 + (kk >> 5)) * DRING + ((t - 1) & 3)) * 4096
                            + (kk & 31) * 128 + 2 * c2;
                        *(float2*)&atile[r * 128 + 2 * c2] = ld_remote2(src);
                    }
                    __syncthreads();
                    gemm64(wt_hh + kt * 64 * NG, atile, 128, accR, accZ, accNH);
                }
            }

            // ---- parent + child waits ----
            if (tid < 8) {
                int grp = tid >> 2, idx = tid & 3;
                int* fp = nullptr; int tgt = 0;
                if (grp == 0) { if (l > 0) { fp = &A.done[((l - 1) * 4 + idx) * 16]; tgt = t + 1; } }
                else          { if (t >= DRING && l < A.NL - 1)
                                { fp = &A.done[((l + 1) * 4 + idx) * 16]; tgt = t - DRING + 1; } }
                if (fp) wait_flag(fp, tgt);
            }
            __syncthreads();

            // ---- ih: stage + gemm ----
            const int nkt = (l == 0 && A.firstLayer == 0) ? 1 : 2;
            for (int kt = 0; kt < nkt; ++kt) {
                if (kt) __syncthreads();
                if (l == 0) {
                    const float* src = A.seqIn + (size_t)t * A.seqTs + (size_t)kt * 64 * 128;
                    for (int i = tid; i < 2048; i += TPB)
                        *(float4*)&atile[4 * i] = *(const float4*)(src + 4 * i);
                } else {
                    for (int u = tid; u < 4096; u += TPB) {
                        int r = u >> 6, c2 = u & 63;
                        int kk = kt * 64 + r;
                        const float* src = A.rings
                            + ((size_t)((l - 1) * 4 + (kk >> 5)) * DRING + (t & 3)) * 4096
                            + (kk & 31) * 128 + 2 * c2;
                        *(float2*)&atile[r * 128 + 2 * c2] = ld_remote2(src);
                    }
                }
                __syncthreads();
                gemm64(wt_ih + kt * 64 * NG, atile, 128, accR, accZ, accNI);
            }
        }

        // ---- gates + h update + publish (plain stores; release flag covers) ----
        float4 hv[2];
#pragma unroll
        for (int jj = 0; jj < 2; ++jj) {
            float* hp = (float*)&hv[jj];
#pragma unroll
            for (int bb = 0; bb < 4; ++bb) {
                float r = sigmoid_f(accR[jj][bb] + bR[jj]);
                float z = sigmoid_f(accZ[jj][bb] + bZ[jj]);
                float n = tanh_f(accNI[jj][bb] + bNI[jj] + r * (accNH[jj][bb] + bNH[jj]));
                float h = (1.0f - z) * n + z * hprev[jj][bb];
                hprev[jj][bb] = h;
                hp[bb] = h;
            }
        }
        float* slot = A.rings + ((size_t)rb * DRING + (t & 3)) * 4096;
        if (STACK == 2) {
            *(float4*)&slot[jl0 * 128 + b0] = hv[0];
            *(float4*)&slot[jl1 * 128 + b0] = hv[1];
            if (A.seqOut && l == A.NL - 1) {
                *(float4*)&A.seqOut[(size_t)t * 16384 + (32 * part + jl0) * 128 + b0] = hv[0];
                *(float4*)&A.seqOut[(size_t)t * 16384 + (32 * part + jl1) * 128 + b0] = hv[1];
            }
        } else {
            *(float4*)&slot[jl0 * 64 + b0] = hv[0];
            *(float4*)&slot[jl1 * 64 + b0] = hv[1];
            *(float4*)&hbuf[jl0 * 64 + b0] = hv[0];
            *(float4*)&hbuf[jl1 * 64 + b0] = hv[1];
            if (A.seqOut && l == A.NL - 1) {
                *(float4*)&A.seqOut[(size_t)t * 16384 + jl0 * 128 + 64 * part + b0] = hv[0];
                *(float4*)&A.seqOut[(size_t)t * 16384 + jl1 * 128 + 64 * part + b0] = hv[1];
            }
            if (STACK == 3 && l == A.NL - 1 && t == 95 && A.hFinal) {
                *(float4*)&A.hFinal[jl0 * 128 + 64 * part + b0] = hv[0];
                *(float4*)&A.hFinal[jl1 * 128 + 64 * part + b0] = hv[1];
            }
        }
        __syncthreads();   // drains vmcnt: ring/seq stores complete before flag
        if (tid == 0)
            __hip_atomic_store(&A.done[rb * 16], t + 1,
                               __ATOMIC_RELEASE, __HIP_MEMORY_SCOPE_AGENT);
    }
}

__global__ void xprep_kernel(const float* __restrict__ x, float* __restrict__ seqA)
{
    int i = blockIdx.x * 256 + threadIdx.x;
    if (i < 128 * 96 * 3) {
        int b = i / 288, r = i - b * 288;
        int t = r / 3, k = r - 3 * t;
        seqA[(size_t)t * 8192 + k * 128 + b] = x[i];
    }
}

__global__ __launch_bounds__(256) void head_kernel(
    const float* __restrict__ hF,
    const float* __restrict__ d1w, const float* __restrict__ d1b,
    const float* __restrict__ d2w, const float* __restrict__ d2b,
    const float* __restrict__ d3w, const float* __restrict__ d3b,
    float* __restrict__ out)
{
    const int b = blockIdx.x, tid = threadIdx.x;
    __shared__ float h1[64], h2[32];
    if (tid < 64) {
        float s = d1b[tid];
        for (int k = 0; k < 64; ++k) s += d1w[tid * 64 + k] * hF[k * 128 + b];
        h1[tid] = fmaxf(s, 0.0f);
    }
    __syncthreads();
    if (tid < 32) {
        float s = d2b[tid];
        for (int k = 0; k < 64; ++k) s += d2w[tid * 64 + k] * h1[k];
        h2[tid] = fmaxf(s, 0.0f);
    }
    __syncthreads();
    if (tid < 250) {
        float s = d3b[tid];
        for (int k = 0; k < 32; ++k) s += d3w[tid * 32 + k] * h2[k];
        out[b * 250 + tid] = fmaxf(s, 0.0f);
    }
}

extern "C" void kernel_launch(void* const* d_in, const int* in_sizes, int n_in,
                              void* d_out, int out_size, void* d_ws, size_t ws_size,
                              hipStream_t stream)
{
    const float* x       = (const float*)d_in[0];
    const float* g1_wih0 = (const float*)d_in[1];  const float* g1_bih0 = (const float*)d_in[2];
    const float* g1_whh0 = (const float*)d_in[3];  const float* g1_bhh0 = (const float*)d_in[4];
    const float* g1_wih  = (const float*)d_in[5];  const float* g1_bih  = (const float*)d_in[6];
    const float* g1_whh  = (const float*)d_in[7];  const float* g1_bhh  = (const float*)d_in[8];
    const float* g2_wih0 = (const float*)d_in[9];  const float* g2_bih0 = (const float*)d_in[10];
    const float* g2_whh0 = (const float*)d_in[11]; const float* g2_bhh0 = (const float*)d_in[12];
    const float* g2_wih  = (const float*)d_in[13]; const float* g2_bih  = (const float*)d_in[14];
    const float* g2_whh  = (const float*)d_in[15]; const float* g2_bhh  = (const float*)d_in[16];
    const float* g3_wih0 = (const float*)d_in[17]; const float* g3_bih0 = (const float*)d_in[18];
    const float* g3_whh0 = (const float*)d_in[19]; const float* g3_bhh0 = (const float*)d_in[20];
    const float* g3_wih  = (const float*)d_in[21]; const float* g3_bih  = (const float*)d_in[22];
    const float* g3_whh  = (const float*)d_in[23]; const float* g3_bhh  = (const float*)d_in[24];
    const float* d1w = (const float*)d_in[25]; const float* d1b = (const float*)d_in[26];
    const float* d2w = (const float*)d_in[27]; const float* d2b = (const float*)d_in[28];
    const float* d3w = (const float*)d_in[29]; const float* d3b = (const float*)d_in[30];

    float* wsf = (float*)d_ws;
    const size_t RINGS = (size_t)192 * DRING * 4096;
    const size_t B1SZ  = (size_t)96 * 128 * 128;
    const size_t SEQA  = (size_t)96 * 64 * 128;
    float* rings  = wsf;
    float* B1     = rings + RINGS;
    float* B2     = B1 + B1SZ;
    float* seqA   = B2 + B1SZ;
    float* hFinal = seqA + SEQA;
    int*   flags  = (int*)(hFinal + 8192);

    size_t zero_bytes = (B1SZ * 2 + SEQA + 8192) * sizeof(float) + 4 * 192 * 16 * sizeof(int);
    hipMemsetAsync(B1, 0, zero_bytes, stream);

    xprep_kernel<<<dim3(144), dim3(256), 0, stream>>>(x, seqA);

    PassArgs P;
    P = {g1_wih0, g1_bih0, g1_whh0, g1_bhh0, g1_wih, g1_bih, g1_whh, g1_bhh,
         0, 96, seqA, 8192, B1, nullptr, rings, flags + 0 * 192 * 16};
    pass_kernel<1><<<dim3(192), dim3(TPB), 0, stream>>>(P);

    P = {g2_wih0, g2_bih0, g2_whh0, g2_bhh0, g2_wih, g2_bih, g2_whh, g2_bhh,
         0, 48, B1, 16384, B2, nullptr, rings, flags + 1 * 192 * 16};
    pass_kernel<2><<<dim3(192), dim3(TPB), 0, stream>>>(P);

    P = {g2_wih0, g2_bih0, g2_whh0, g2_bhh0, g2_wih, g2_bih, g2_whh, g2_bhh,
         48, 48, B2, 16384, B1, nullptr, rings, flags + 2 * 192 * 16};
    pass_kernel<2><<<dim3(192), dim3(TPB), 0, stream>>>(P);

    P = {g3_wih0, g3_bih0, g3_whh0, g3_bhh0, g3_wih, g3_bih, g3_whh, g3_bhh,
         0, 96, B1, 16384, nullptr, hFinal, rings, flags + 3 * 192 * 16};
    pass_kernel<3><<<dim3(192), dim3(TPB), 0, stream>>>(P);

    head_kernel<<<dim3(128), dim3(256), 0, stream>>>(hFinal, d1w, d1b, d2w, d2b, d3w, d3b,
                                                     (float*)d_out);
}

// Round 5
// 13077.875 us; speedup vs baseline: 2.5126x; 1.0693x over previous
//
#include <hip/hip_runtime.h>

// GRU_781684048417 — round 5: layer-pipelined wavefront, zero-cache-maintenance
// sync protocol.
//
// Topology identical to rounds 3/4 (one block per (layer, slice); LDS-stationary
// weights; depth-4 rings; 4 serialized passes of 192 co-resident blocks).
// Round 4: 21 us/link vs ~5 us compute; remaining overhead = per-step
// buffer_wbl2 (RELEASE flag store) + buffer_inv (ACQUIRE on wait). This round:
//  - ALL cross-block data (rings) moves via relaxed agent-scope 8B atomics
//    (sc1 -> serviced at the memory-side coherence point; round 4's FETCH_SIZE
//    jump proved these bypass the XCD L2).
//  - Flag publish: __syncthreads() (per-wave vmcnt(0) drain before s_barrier =>
//    all ring stores at coherence point) + RELAXED flag store. No wbl2.
//  - wait_flag: relaxed polls only. No buffer_inv anywhere in the loop.
//  - Cross-pass buffers (seqA/B1/B2/hFinal) are plain loads/stores: passes are
//    stream-serialized, dispatch boundaries carry implicit flush/inv.

#define TPB 512
#define DRING 4

__device__ __forceinline__ float sigmoid_f(float x) { return 1.0f / (1.0f + __expf(-x)); }
__device__ __forceinline__ float tanh_f(float x)    { return 1.0f - 2.0f / (__expf(2.0f * x) + 1.0f); }

__device__ __forceinline__ void wait_flag(int* fp, int tgt) {
    while (__hip_atomic_load(fp, __ATOMIC_RELAXED, __HIP_MEMORY_SCOPE_AGENT) < tgt)
        __builtin_amdgcn_s_sleep(2);
}
__device__ __forceinline__ float2 ld_remote2(const float* p) {
    unsigned long long u = __hip_atomic_load((const unsigned long long*)p,
                                             __ATOMIC_RELAXED, __HIP_MEMORY_SCOPE_AGENT);
    union { unsigned long long u; float2 f; } c; c.u = u;
    return c.f;
}
__device__ __forceinline__ void st_remote2(float* p, float a, float b) {
    union { unsigned long long u; float f[2]; } c; c.f[0] = a; c.f[1] = b;
    __hip_atomic_store((unsigned long long*)p, c.u,
                       __ATOMIC_RELAXED, __HIP_MEMORY_SCOPE_AGENT);
}

struct PassArgs {
    const float* wih0; const float* bih0; const float* whh0; const float* bhh0;
    const float* wihA; const float* bihA; const float* whhA; const float* bhhA;
    int firstLayer;
    int NL;
    const float* seqIn;
    long seqTs;
    float* seqOut;
    float* hFinal;
    float* rings;            // [192][DRING][4096]
    int* done;               // [192][16]
};

template<int STACK>
__global__ __launch_bounds__(TPB, 2) void pass_kernel(PassArgs A)
{
    constexpr int NG    = (STACK == 2) ? 96 : 192;   // gate rows per block
    constexpr int NB    = (STACK == 2) ? 128 : 64;   // batch rows per block
    constexpr int KH    = (STACK == 2) ? 128 : 64;   // recurrent K
    constexpr int PARTS = (STACK == 2) ? 4 : 2;
    constexpr int JS    = NG / 3;
    constexpr int NGG   = NG / 6;

    __shared__ float wt_hh[KH * NG];
    __shared__ float wt_ih[((STACK == 2) ? 128 : 64) * NG];
    __shared__ float atile[64 * NB];
    __shared__ float hbuf[64 * 64];

    const int tid  = threadIdx.x;
    const int rb   = blockIdx.x;
    const int l    = rb / PARTS;
    const int part = rb % PARTS;
    const int gl   = A.firstLayer + l;

    const int gg = tid & (NGG - 1);
    const int bg = tid / NGG;
    const int jl0 = 2 * gg, jl1 = 2 * gg + 1;
    const int b0 = 4 * bg;

    const float *wih, *bih, *whh, *bhh;
    int din;
    if (gl == 0) { wih = A.wih0; bih = A.bih0; whh = A.whh0; bhh = A.bhh0;
                   din = (STACK == 1) ? 3 : ((STACK == 2) ? 64 : 128); }
    else {
        const int wsz = (STACK == 2) ? 384 * 128 : 192 * 64;
        const int bs  = (STACK == 2) ? 384 : 192;
        wih = A.wihA + (size_t)(gl - 1) * wsz; bih = A.bihA + (size_t)(gl - 1) * bs;
        whh = A.whhA + (size_t)(gl - 1) * wsz; bhh = A.bhhA + (size_t)(gl - 1) * bs;
        din = (STACK == 2) ? 128 : 64;
    }
    const bool wideIH = (STACK == 3) && (gl == 0);

    auto grow = [&](int r) -> int {
        if (STACK == 2) return (r >> 5) * 128 + 32 * part + (r & 31);
        return r;
    };

    for (int i = tid; i < NG * KH; i += TPB) {
        int r = i / KH, k = i - r * KH;
        wt_hh[k * NG + r] = whh[(size_t)grow(r) * KH + k];
    }
    if (!wideIH) {
        constexpr int KI = (STACK == 2) ? 128 : 64;
        for (int i = tid; i < NG * KI; i += TPB) {
            int r = i / KI, k = i - r * KI;
            wt_ih[k * NG + r] = (k < din) ? wih[(size_t)grow(r) * din + k] : 0.0f;
        }
    }

    float bR[2], bZ[2], bNH[2], bNI[2];
#pragma unroll
    for (int jj = 0; jj < 2; ++jj) {
        int jl = jl0 + jj;
        bR[jj]  = bhh[grow(jl)]          + bih[grow(jl)];
        bZ[jj]  = bhh[grow(JS + jl)]     + bih[grow(JS + jl)];
        bNH[jj] = bhh[grow(2 * JS + jl)];
        bNI[jj] = bih[grow(2 * JS + jl)];
    }

    float hprev[2][4];
#pragma unroll
    for (int jj = 0; jj < 2; ++jj)
#pragma unroll
        for (int bb = 0; bb < 4; ++bb) hprev[jj][bb] = 0.0f;

    __syncthreads();

    auto gemm64 = [&](const float* wt, const float* at, int astride,
                      float (&accR)[2][4], float (&accZ)[2][4], float (&accN)[2][4]) {
#pragma unroll 4
        for (int k = 0; k < 64; ++k) {
            const float* wr = wt + k * NG;
            float2 wR = *(const float2*)&wr[jl0];
            float2 wZ = *(const float2*)&wr[JS + jl0];
            float2 wN = *(const float2*)&wr[2 * JS + jl0];
            float4 av = *(const float4*)(at + k * astride + b0);
            float a[4] = {av.x, av.y, av.z, av.w};
#pragma unroll
            for (int bb = 0; bb < 4; ++bb) {
                accR[0][bb] += wR.x * a[bb];  accR[1][bb] += wR.y * a[bb];
                accZ[0][bb] += wZ.x * a[bb];  accZ[1][bb] += wZ.y * a[bb];
                accN[0][bb] += wN.x * a[bb];  accN[1][bb] += wN.y * a[bb];
            }
        }
    };

    for (int t = 0; t < 96; ++t) {
        float accR[2][4] = {}, accZ[2][4] = {}, accNH[2][4] = {}, accNI[2][4] = {};

        if (STACK != 2) {
            // ---- hh first (own LDS state; hides parent flag RTT) ----
            if (t > 0) gemm64(wt_hh, hbuf, 64, accR, accZ, accNH);

            // ---- parent(t) + child-antidep waits ----
            if (tid < 8) {
                int grp = tid >> 2, idx = tid & 3;
                int* fp = nullptr; int tgt = 0;
                if (grp == 0) { if (l > 0 && idx == part)
                                { fp = &A.done[((l - 1) * PARTS + idx) * 16]; tgt = t + 1; } }
                else          { if (t >= DRING && l < A.NL - 1 && idx == part)
                                { fp = &A.done[((l + 1) * PARTS + idx) * 16]; tgt = t - DRING + 1; } }
                if (fp) wait_flag(fp, tgt);
            }
            __syncthreads();

            // ---- ih: stage + gemm ----
            const int nkt = wideIH ? 2 : 1;
            for (int kt = 0; kt < nkt; ++kt) {
                if (kt) __syncthreads();
                if (wideIH) {
                    for (int i = tid; i < 192 * 64; i += TPB) {
                        int r = i >> 6, k = i & 63;
                        wt_ih[k * NG + r] = wih[(size_t)r * 128 + kt * 64 + k];
                    }
                }
                if (l == 0) {
                    const float* src = A.seqIn + (size_t)t * A.seqTs + (size_t)kt * 64 * 128 + 64 * part;
                    for (int i = tid; i < 1024; i += TPB) {
                        int r = i >> 4, seg = i & 15;
                        *(float4*)&atile[r * 64 + seg * 4] = *(const float4*)(src + r * 128 + seg * 4);
                    }
                } else {
                    const float* slot = A.rings + ((size_t)((l - 1) * PARTS + part) * DRING + (t & 3)) * 4096;
                    for (int u = tid; u < 2048; u += TPB)
                        *(float2*)&atile[2 * u] = ld_remote2(slot + 2 * u);
                }
                __syncthreads();
                gemm64(wt_ih, atile, 64, accR, accZ, accNI);
            }
        } else {
            // ---- STACK 2: sibling wait + hh from rings ----
            if (t > 0) {
                if (tid < 4 && tid != part)
                    wait_flag(&A.done[(l * 4 + tid) * 16], t);
                __syncthreads();
                for (int kt = 0; kt < 2; ++kt) {
                    if (kt) __syncthreads();
                    for (int u = tid; u < 4096; u += TPB) {
                        int r = u >> 6, c2 = u & 63;
                        int kk = kt * 64 + r;
                        const float* src = A.rings
                            + ((size_t)(l * 4 + (kk >> 5)) * DRING + ((t - 1) & 3)) * 4096
                            + (kk & 31) * 128 + 2 * c2;
                        *(float2*)&atile[r * 128 + 2 * c2] = ld_remote2(src);
                    }
                    __syncthreads();
                    gemm64(wt_hh + kt * 64 * NG, atile, 128, accR, accZ, accNH);
                }
            }

            // ---- parent + child waits ----
            if (tid < 8) {
                int grp = tid >> 2, idx = tid & 3;
                int* fp = nullptr; int tgt = 0;
                if (grp == 0) { if (l > 0) { fp = &A.done[((l - 1) * 4 + idx) * 16]; tgt = t + 1; } }
                else          { if (t >= DRING && l < A.NL - 1)
                                { fp = &A.done[((l + 1) * 4 + idx) * 16]; tgt = t - DRING + 1; } }
                if (fp) wait_flag(fp, tgt);
            }
            __syncthreads();

            // ---- ih: stage + gemm ----
            const int nkt = (l == 0 && A.firstLayer == 0) ? 1 : 2;
            for (int kt = 0; kt < nkt; ++kt) {
                if (kt) __syncthreads();
                if (l == 0) {
                    const float* src = A.seqIn + (size_t)t * A.seqTs + (size_t)kt * 64 * 128;
                    for (int i = tid; i < 2048; i += TPB)
                        *(float4*)&atile[4 * i] = *(const float4*)(src + 4 * i);
                } else {
                    for (int u = tid; u < 4096; u += TPB) {
                        int r = u >> 6, c2 = u & 63;
                        int kk = kt * 64 + r;
                        const float* src = A.rings
                            + ((size_t)((l - 1) * 4 + (kk >> 5)) * DRING + (t & 3)) * 4096
                            + (kk & 31) * 128 + 2 * c2;
                        *(float2*)&atile[r * 128 + 2 * c2] = ld_remote2(src);
                    }
                }
                __syncthreads();
                gemm64(wt_ih + kt * 64 * NG, atile, 128, accR, accZ, accNI);
            }
        }

        // ---- gates + h update + publish ----
        float4 hv[2];
#pragma unroll
        for (int jj = 0; jj < 2; ++jj) {
            float* hp = (float*)&hv[jj];
#pragma unroll
            for (int bb = 0; bb < 4; ++bb) {
                float r = sigmoid_f(accR[jj][bb] + bR[jj]);
                float z = sigmoid_f(accZ[jj][bb] + bZ[jj]);
                float n = tanh_f(accNI[jj][bb] + bNI[jj] + r * (accNH[jj][bb] + bNH[jj]));
                float h = (1.0f - z) * n + z * hprev[jj][bb];
                hprev[jj][bb] = h;
                hp[bb] = h;
            }
        }
        // ring publish via sc1 atomics (coherence point; no wbl2 needed)
        float* slot = A.rings + ((size_t)rb * DRING + (t & 3)) * 4096;
        if (STACK == 2) {
            st_remote2(&slot[jl0 * 128 + b0],     hv[0].x, hv[0].y);
            st_remote2(&slot[jl0 * 128 + b0 + 2], hv[0].z, hv[0].w);
            st_remote2(&slot[jl1 * 128 + b0],     hv[1].x, hv[1].y);
            st_remote2(&slot[jl1 * 128 + b0 + 2], hv[1].z, hv[1].w);
            if (A.seqOut && l == A.NL - 1) {
                *(float4*)&A.seqOut[(size_t)t * 16384 + (32 * part + jl0) * 128 + b0] = hv[0];
                *(float4*)&A.seqOut[(size_t)t * 16384 + (32 * part + jl1) * 128 + b0] = hv[1];
            }
        } else {
            st_remote2(&slot[jl0 * 64 + b0],     hv[0].x, hv[0].y);
            st_remote2(&slot[jl0 * 64 + b0 + 2], hv[0].z, hv[0].w);
            st_remote2(&slot[jl1 * 64 + b0],     hv[1].x, hv[1].y);
            st_remote2(&slot[jl1 * 64 + b0 + 2], hv[1].z, hv[1].w);
            *(float4*)&hbuf[jl0 * 64 + b0] = hv[0];
            *(float4*)&hbuf[jl1 * 64 + b0] = hv[1];
            if (A.seqOut && l == A.NL - 1) {
                *(float4*)&A.seqOut[(size_t)t * 16384 + jl0 * 128 + 64 * part + b0] = hv[0];
                *(float4*)&A.seqOut[(size_t)t * 16384 + jl1 * 128 + 64 * part + b0] = hv[1];
            }
            if (STACK == 3 && l == A.NL - 1 && t == 95 && A.hFinal) {
                *(float4*)&A.hFinal[jl0 * 128 + 64 * part + b0] = hv[0];
                *(float4*)&A.hFinal[jl1 * 128 + 64 * part + b0] = hv[1];
            }
        }
        // barrier drains each wave's vmcnt before s_barrier => all ring stores
        // are at the coherence point before the (relaxed) flag store below.
        __syncthreads();
        if (tid == 0)
            __hip_atomic_store(&A.done[rb * 16], t + 1,
                               __ATOMIC_RELAXED, __HIP_MEMORY_SCOPE_AGENT);
    }
}

__global__ void xprep_kernel(const float* __restrict__ x, float* __restrict__ seqA)
{
    int i = blockIdx.x * 256 + threadIdx.x;
    if (i < 128 * 96 * 3) {
        int b = i / 288, r = i - b * 288;
        int t = r / 3, k = r - 3 * t;
        seqA[(size_t)t * 8192 + k * 128 + b] = x[i];
    }
}

__global__ __launch_bounds__(256) void head_kernel(
    const float* __restrict__ hF,
    const float* __restrict__ d1w, const float* __restrict__ d1b,
    const float* __restrict__ d2w, const float* __restrict__ d2b,
    const float* __restrict__ d3w, const float* __restrict__ d3b,
    float* __restrict__ out)
{
    const int b = blockIdx.x, tid = threadIdx.x;
    __shared__ float h1[64], h2[32];
    if (tid < 64) {
        float s = d1b[tid];
        for (int k = 0; k < 64; ++k) s += d1w[tid * 64 + k] * hF[k * 128 + b];
        h1[tid] = fmaxf(s, 0.0f);
    }
    __syncthreads();
    if (tid < 32) {
        float s = d2b[tid];
        for (int k = 0; k < 64; ++k) s += d2w[tid * 64 + k] * h1[k];
        h2[tid] = fmaxf(s, 0.0f);
    }
    __syncthreads();
    if (tid < 250) {
        float s = d3b[tid];
        for (int k = 0; k < 32; ++k) s += d3w[tid * 32 + k] * h2[k];
        out[b * 250 + tid] = fmaxf(s, 0.0f);
    }
}

extern "C" void kernel_launch(void* const* d_in, const int* in_sizes, int n_in,
                              void* d_out, int out_size, void* d_ws, size_t ws_size,
                              hipStream_t stream)
{
    const float* x       = (const float*)d_in[0];
    const float* g1_wih0 = (const float*)d_in[1];  const float* g1_bih0 = (const float*)d_in[2];
    const float* g1_whh0 = (const float*)d_in[3];  const float* g1_bhh0 = (const float*)d_in[4];
    const float* g1_wih  = (const float*)d_in[5];  const float* g1_bih  = (const float*)d_in[6];
    const float* g1_whh  = (const float*)d_in[7];  const float* g1_bhh  = (const float*)d_in[8];
    const float* g2_wih0 = (const float*)d_in[9];  const float* g2_bih0 = (const float*)d_in[10];
    const float* g2_whh0 = (const float*)d_in[11]; const float* g2_bhh0 = (const float*)d_in[12];
    const float* g2_wih  = (const float*)d_in[13]; const float* g2_bih  = (const float*)d_in[14];
    const float* g2_whh  = (const float*)d_in[15]; const float* g2_bhh  = (const float*)d_in[16];
    const float* g3_wih0 = (const float*)d_in[17]; const float* g3_bih0 = (const float*)d_in[18];
    const float* g3_whh0 = (const float*)d_in[19]; const float* g3_bhh0 = (const float*)d_in[20];
    const float* g3_wih  = (const float*)d_in[21]; const float* g3_bih  = (const float*)d_in[22];
    const float* g3_whh  = (const float*)d_in[23]; const float* g3_bhh  = (const float*)d_in[24];
    const float* d1w = (const float*)d_in[25]; const float* d1b = (const float*)d_in[26];
    const float* d2w = (const float*)d_in[27]; const float* d2b = (const float*)d_in[28];
    const float* d3w = (const float*)d_in[29]; const float* d3b = (const float*)d_in[30];

    float* wsf = (float*)d_ws;
    const size_t RINGS = (size_t)192 * DRING * 4096;
    const size_t B1SZ  = (size_t)96 * 128 * 128;
    const size_t SEQA  = (size_t)96 * 64 * 128;
    float* rings  = wsf;
    float* B1     = rings + RINGS;
    float* B2     = B1 + B1SZ;
    float* seqA   = B2 + B1SZ;
    float* hFinal = seqA + SEQA;
    int*   flags  = (int*)(hFinal + 8192);

    size_t zero_bytes = (B1SZ * 2 + SEQA + 8192) * sizeof(float) + 4 * 192 * 16 * sizeof(int);
    hipMemsetAsync(B1, 0, zero_bytes, stream);

    xprep_kernel<<<dim3(144), dim3(256), 0, stream>>>(x, seqA);

    PassArgs P;
    P = {g1_wih0, g1_bih0, g1_whh0, g1_bhh0, g1_wih, g1_bih, g1_whh, g1_bhh,
         0, 96, seqA, 8192, B1, nullptr, rings, flags + 0 * 192 * 16};
    pass_kernel<1><<<dim3(192), dim3(TPB), 0, stream>>>(P);

    P = {g2_wih0, g2_bih0, g2_whh0, g2_bhh0, g2_wih, g2_bih, g2_whh, g2_bhh,
         0, 48, B1, 16384, B2, nullptr, rings, flags + 1 * 192 * 16};
    pass_kernel<2><<<dim3(192), dim3(TPB), 0, stream>>>(P);

    P = {g2_wih0, g2_bih0, g2_whh0, g2_bhh0, g2_wih, g2_bih, g2_whh, g2_bhh,
         48, 48, B2, 16384, B1, nullptr, rings, flags + 2 * 192 * 16};
    pass_kernel<2><<<dim3(192), dim3(TPB), 0, stream>>>(P);

    P = {g3_wih0, g3_bih0, g3_whh0, g3_bhh0, g3_wih, g3_bih, g3_whh, g3_bhh,
         0, 96, B1, 16384, nullptr, hFinal, rings, flags + 3 * 192 * 16};
    pass_kernel<3><<<dim3(192), dim3(TPB), 0, stream>>>(P);

    head_kernel<<<dim3(128), dim3(256), 0, stream>>>(hFinal, d1w, d1b, d2w, d2b, d3w, d3b,
                                                     (float*)d_out);
}